// Round 1
// baseline (293.122 us; speedup 1.0000x reference)
//
#include <hip/hip_runtime.h>

typedef short s16x8 __attribute__((ext_vector_type(8)));
typedef short s16x4 __attribute__((ext_vector_type(4)));
typedef float f32x4 __attribute__((ext_vector_type(4)));

#define B_   4
#define N_   1024
#define C_   1024
#define H_   16
#define D_   64
#define FFH_ 2730
#define FFP_ 2752
#define M_   4096

__device__ __forceinline__ short f2bf(float f) {
  unsigned u = __float_as_uint(f);
  u += 0x7fff + ((u >> 16) & 1);           // RNE to bf16
  return (short)(unsigned short)(u >> 16);
}
__device__ __forceinline__ float silu(float x) { return x / (1.f + __expf(-x)); }

// ---------------- weight conversion ----------------
__global__ void cvt_bf(const float* __restrict__ s, short* __restrict__ d, const int n4) {
  for (int i = blockIdx.x * 256 + threadIdx.x; i < n4; i += gridDim.x * 256) {
    const float4 v = ((const float4*)s)[i];
    s16x4 o;
    o[0] = f2bf(v.x); o[1] = f2bf(v.y); o[2] = f2bf(v.z); o[3] = f2bf(v.w);
    *(s16x4*)(d + (size_t)i * 4) = o;
  }
}

__global__ void cvt_w3(const float* __restrict__ s, short* __restrict__ d) {
  const int col = blockIdx.x * 256 + threadIdx.x;
  const int row = blockIdx.y;
  if (col < FFP_)
    d[(size_t)row * FFP_ + col] = (col < FFH_) ? f2bf(s[(size_t)row * FFH_ + col]) : (short)0;
}

// ---------------- ada = silu(c) @ ada_w.T + ada_b ----------------
__global__ void ada_gemm(const float* __restrict__ c, const float* __restrict__ aw,
                         const float* __restrict__ ab, float* __restrict__ ada) {
  const int j = blockIdx.x;         // 0..6143
  const int l = threadIdx.x;        // 0..63
  float acc[4] = {0.f, 0.f, 0.f, 0.f};
  const float4* wr = (const float4*)(aw + (size_t)j * 1024);
  #pragma unroll
  for (int p = 0; p < 4; ++p) {
    const float4 wv = wr[p * 64 + l];
    #pragma unroll
    for (int b = 0; b < 4; ++b) {
      const float4 cv = ((const float4*)(c + b * 1024))[p * 64 + l];
      acc[b] += silu(cv.x) * wv.x + silu(cv.y) * wv.y + silu(cv.z) * wv.z + silu(cv.w) * wv.w;
    }
  }
  #pragma unroll
  for (int b = 0; b < 4; ++b) {
    float a = acc[b];
    #pragma unroll
    for (int m = 1; m < 64; m <<= 1) a += __shfl_xor(a, m);
    if (l == 0) ada[b * 6144 + j] = a + ab[j];
  }
}

// ---------------- fused rmsnorm + modulate -> bf16 ----------------
__global__ void rmsmod(const float* __restrict__ x, const float* __restrict__ wn,
                       const float* __restrict__ ada, const int sOff, const int gOff,
                       short* __restrict__ out) {
  const int row = blockIdx.x;          // 0..4095
  const int b = row >> 10;
  const int t = threadIdx.x;           // 0..255
  const float4 v = ((const float4*)(x + (size_t)row * 1024))[t];
  float ss = v.x * v.x + v.y * v.y + v.z * v.z + v.w * v.w;
  #pragma unroll
  for (int m = 1; m < 64; m <<= 1) ss += __shfl_xor(ss, m);
  __shared__ float red[4];
  if ((t & 63) == 0) red[t >> 6] = ss;
  __syncthreads();
  const float rs = rsqrtf((red[0] + red[1] + red[2] + red[3]) * (1.f / 1024.f) + 1e-6f);
  const int j = t * 4;
  const float* sp = ada + b * 6144 + sOff + j;
  const float* gp = ada + b * 6144 + gOff + j;
  s16x4 o;
  o[0] = f2bf(v.x * rs * wn[j + 0] * (1.f + gp[0]) + sp[0]);
  o[1] = f2bf(v.y * rs * wn[j + 1] * (1.f + gp[1]) + sp[1]);
  o[2] = f2bf(v.z * rs * wn[j + 2] * (1.f + gp[2]) + sp[2]);
  o[3] = f2bf(v.w * rs * wn[j + 3] * (1.f + gp[3]) + sp[3]);
  *(s16x4*)(out + (size_t)row * 1024 + j) = o;
}

// ---------------- generic 128x128 bf16 GEMM, B^T (weights) layout ----------------
// EPI 0: out = acc + bias[n]                      (qkv)
// EPI 1: out = resid[m,n] + adav[b,n]*(acc+bias)  (proj / w3)
template <int EPI>
__launch_bounds__(256, 2)
__global__ void gemm_bt(const short* __restrict__ A, const short* __restrict__ Bt,
                        const int K, const int ldo,
                        const float* __restrict__ bias,
                        const float* __restrict__ adav,
                        const float* __restrict__ resid,
                        float* __restrict__ outF) {
  __shared__ short As[128 * 64];
  __shared__ short Bs[128 * 64];
  const int t = threadIdx.x;
  const int l = t & 63;
  const int w = t >> 6;
  const int wr = (w >> 1) * 64, wc = (w & 1) * 64;
  const int m0 = blockIdx.y * 128;
  const int n0 = blockIdx.x * 128;
  const int nT = K >> 6;
  const int sr = t >> 1;          // staging row 0..127
  const int sc = (t & 1) * 4;     // staging 16B-chunk base

  f32x4 acc[4][4];
  const f32x4 z4 = {0.f, 0.f, 0.f, 0.f};
  #pragma unroll
  for (int i = 0; i < 4; ++i)
    #pragma unroll
    for (int j = 0; j < 4; ++j) acc[i][j] = z4;

  const short* gA = A + (size_t)(m0 + sr) * K + sc * 8;
  const short* gB = Bt + (size_t)(n0 + sr) * K + sc * 8;

  s16x8 ra[4], rb[4];
  #pragma unroll
  for (int p = 0; p < 4; ++p) {
    ra[p] = *(const s16x8*)(gA + p * 8);
    rb[p] = *(const s16x8*)(gB + p * 8);
  }

  for (int kt = 0; kt < nT; ++kt) {
    if (kt) __syncthreads();
    #pragma unroll
    for (int p = 0; p < 4; ++p) {
      const int cs = ((sc + p) ^ (sr & 7)) << 3;
      *(s16x8*)&As[sr * 64 + cs] = ra[p];
      *(s16x8*)&Bs[sr * 64 + cs] = rb[p];
    }
    __syncthreads();
    if (kt + 1 < nT) {
      const int ko = (kt + 1) * 64;
      #pragma unroll
      for (int p = 0; p < 4; ++p) {
        ra[p] = *(const s16x8*)(gA + ko + p * 8);
        rb[p] = *(const s16x8*)(gB + ko + p * 8);
      }
    }
    #pragma unroll
    for (int kk = 0; kk < 2; ++kk) {
      const int c16 = kk * 4 + (l >> 4);
      s16x8 af[4], bfr[4];
      #pragma unroll
      for (int mf = 0; mf < 4; ++mf) {
        const int r = wr + mf * 16 + (l & 15);
        af[mf] = *(const s16x8*)&As[r * 64 + ((c16 ^ (r & 7)) << 3)];
      }
      #pragma unroll
      for (int nf = 0; nf < 4; ++nf) {
        const int r = wc + nf * 16 + (l & 15);
        bfr[nf] = *(const s16x8*)&Bs[r * 64 + ((c16 ^ (r & 7)) << 3)];
      }
      #pragma unroll
      for (int mf = 0; mf < 4; ++mf)
        #pragma unroll
        for (int nf = 0; nf < 4; ++nf)
          acc[mf][nf] = __builtin_amdgcn_mfma_f32_16x16x32_bf16(af[mf], bfr[nf], acc[mf][nf], 0, 0, 0);
    }
  }

  const int bIdx = m0 >> 10;
  #pragma unroll
  for (int mf = 0; mf < 4; ++mf) {
    const int row = m0 + wr + mf * 16 + ((l >> 4) << 2);
    #pragma unroll
    for (int nf = 0; nf < 4; ++nf) {
      const int col = n0 + wc + nf * 16 + (l & 15);
      const float bsv = bias[col];
      #pragma unroll
      for (int i = 0; i < 4; ++i) {
        float v = acc[mf][nf][i] + bsv;
        if (EPI == 1)
          v = resid[(size_t)(row + i) * 1024 + col] + adav[bIdx * 6144 + col] * v;
        outF[(size_t)(row + i) * ldo + col] = v;
      }
    }
  }
}

// ---------------- w12 GEMM with fused SwiGLU epilogue ----------------
// Block tile: 128 rows x 64 cols (per half). Computes silu(x@W1+b1)*(x@W2+b2) -> bf16, padded to FFP_.
__launch_bounds__(256, 2)
__global__ void gemm_w12(const short* __restrict__ A, const short* __restrict__ Bt,
                         const float* __restrict__ bias, short* __restrict__ outH) {
  __shared__ short As[128 * 64];
  __shared__ short B1s[64 * 64];
  __shared__ short B2s[64 * 64];
  const int t = threadIdx.x;
  const int l = t & 63;
  const int w = t >> 6;
  const int wr = (w >> 1) * 64, wc = (w & 1) * 32;
  const int m0 = blockIdx.y * 128;
  const int n0 = blockIdx.x * 64;
  const int sr = t >> 1, sc = (t & 1) * 4;
  const int sr2 = t >> 2, sc2 = (t & 3) * 2;
  const int jr = (n0 + sr2 < FFH_) ? (n0 + sr2) : (FFH_ - 1);   // clamp, zeroed in epilogue

  f32x4 a1[4][2], a2[4][2];
  const f32x4 z4 = {0.f, 0.f, 0.f, 0.f};
  #pragma unroll
  for (int i = 0; i < 4; ++i)
    #pragma unroll
    for (int j = 0; j < 2; ++j) { a1[i][j] = z4; a2[i][j] = z4; }

  const short* gA = A + (size_t)(m0 + sr) * 1024 + sc * 8;
  const short* gB1 = Bt + (size_t)jr * 1024 + sc2 * 8;
  const short* gB2 = Bt + (size_t)(jr + FFH_) * 1024 + sc2 * 8;

  s16x8 ra[4], rb1[2], rb2[2];
  #pragma unroll
  for (int p = 0; p < 4; ++p) ra[p] = *(const s16x8*)(gA + p * 8);
  #pragma unroll
  for (int p = 0; p < 2; ++p) { rb1[p] = *(const s16x8*)(gB1 + p * 8); rb2[p] = *(const s16x8*)(gB2 + p * 8); }

  for (int kt = 0; kt < 16; ++kt) {
    if (kt) __syncthreads();
    #pragma unroll
    for (int p = 0; p < 4; ++p)
      *(s16x8*)&As[sr * 64 + (((sc + p) ^ (sr & 7)) << 3)] = ra[p];
    #pragma unroll
    for (int p = 0; p < 2; ++p) {
      const int cs = ((sc2 + p) ^ (sr2 & 7)) << 3;
      *(s16x8*)&B1s[sr2 * 64 + cs] = rb1[p];
      *(s16x8*)&B2s[sr2 * 64 + cs] = rb2[p];
    }
    __syncthreads();
    if (kt < 15) {
      const int ko = (kt + 1) * 64;
      #pragma unroll
      for (int p = 0; p < 4; ++p) ra[p] = *(const s16x8*)(gA + ko + p * 8);
      #pragma unroll
      for (int p = 0; p < 2; ++p) { rb1[p] = *(const s16x8*)(gB1 + ko + p * 8); rb2[p] = *(const s16x8*)(gB2 + ko + p * 8); }
    }
    #pragma unroll
    for (int kk = 0; kk < 2; ++kk) {
      const int c16 = kk * 4 + (l >> 4);
      s16x8 af[4], b1f[2], b2f[2];
      #pragma unroll
      for (int mf = 0; mf < 4; ++mf) {
        const int r = wr + mf * 16 + (l & 15);
        af[mf] = *(const s16x8*)&As[r * 64 + ((c16 ^ (r & 7)) << 3)];
      }
      #pragma unroll
      for (int nf = 0; nf < 2; ++nf) {
        const int r = wc + nf * 16 + (l & 15);
        const int idx = r * 64 + ((c16 ^ (r & 7)) << 3);
        b1f[nf] = *(const s16x8*)&B1s[idx];
        b2f[nf] = *(const s16x8*)&B2s[idx];
      }
      #pragma unroll
      for (int mf = 0; mf < 4; ++mf)
        #pragma unroll
        for (int nf = 0; nf < 2; ++nf) {
          a1[mf][nf] = __builtin_amdgcn_mfma_f32_16x16x32_bf16(af[mf], b1f[nf], a1[mf][nf], 0, 0, 0);
          a2[mf][nf] = __builtin_amdgcn_mfma_f32_16x16x32_bf16(af[mf], b2f[nf], a2[mf][nf], 0, 0, 0);
        }
    }
  }

  #pragma unroll
  for (int mf = 0; mf < 4; ++mf) {
    const int row = m0 + wr + mf * 16 + ((l >> 4) << 2);
    #pragma unroll
    for (int nf = 0; nf < 2; ++nf) {
      const int col = n0 + wc + nf * 16 + (l & 15);
      if (col < FFP_) {
        const bool real = col < FFH_;
        const float bb1 = real ? bias[col] : 0.f;
        const float bb2 = real ? bias[col + FFH_] : 0.f;
        #pragma unroll
        for (int i = 0; i < 4; ++i) {
          float o = 0.f;
          if (real) {
            const float v1 = a1[mf][nf][i] + bb1;
            const float v2 = a2[mf][nf][i] + bb2;
            o = silu(v1) * v2;
          }
          outH[(size_t)(row + i) * FFP_ + col] = f2bf(o);
        }
      }
    }
  }
}

// ---------------- q/k rmsnorm (+1/sqrt(D) into q) -> bf16 (B,H,N,D) ----------------
__global__ void qk_post(const float* __restrict__ qkvf, const float* __restrict__ qnw,
                        const float* __restrict__ knw, short* __restrict__ qb,
                        short* __restrict__ kb) {
  const int gw = blockIdx.x * 4 + (threadIdx.x >> 6);
  const int l = threadIdx.x & 63;
  const int h = gw & 15, n = (gw >> 4) & 1023, b = gw >> 14;
  const size_t base = (size_t)(b * 1024 + n) * 3072 + h * 64 + l;
  const float qv = qkvf[base];
  const float kv = qkvf[base + 1024];
  float sq = qv * qv, sk = kv * kv;
  #pragma unroll
  for (int m = 1; m < 64; m <<= 1) { sq += __shfl_xor(sq, m); sk += __shfl_xor(sk, m); }
  const float rq = rsqrtf(sq * (1.f / 64.f) + 1e-6f);
  const float rk = rsqrtf(sk * (1.f / 64.f) + 1e-6f);
  const size_t o = ((size_t)(b * 16 + h) * 1024 + n) * 64 + l;
  qb[o] = f2bf(qv * rq * qnw[l] * 0.125f);   // fold 1/sqrt(64)
  kb[o] = f2bf(kv * rk * knw[l]);
}

// ---------------- V transpose -> bf16 (B,H,D,N) ----------------
__global__ void v_trans(const float* __restrict__ qkvf, short* __restrict__ vt) {
  __shared__ float ld[64][65];
  const int t = threadIdx.x;
  const int bh = blockIdx.y, b = bh >> 4, h = bh & 15;
  const int n0 = blockIdx.x * 64;
  const int nl = t >> 2, cb = (t & 3) * 16;
  const float* src = qkvf + (size_t)(b * 1024 + n0 + nl) * 3072 + 2048 + h * 64 + cb;
  #pragma unroll
  for (int p = 0; p < 16; ++p) ld[nl][cb + p] = src[p];
  __syncthreads();
  const int d = t >> 2, np = (t & 3) * 16;
  short* dst = vt + (size_t)(bh * 64 + d) * 1024 + n0 + np;
  #pragma unroll
  for (int p = 0; p < 16; ++p) dst[p] = f2bf(ld[np + p][d]);
}

// ---------------- flash attention ----------------
__launch_bounds__(256, 2)
__global__ void attn(const short* __restrict__ qb, const short* __restrict__ kb,
                     const short* __restrict__ vt, short* __restrict__ ob) {
  __shared__ short Ks[64 * 64];
  __shared__ short Vs[64 * 64];
  __shared__ short Pl[4][32 * 64];
  const int t = threadIdx.x, l = t & 63, w = t >> 6;
  const int bh = blockIdx.y, b = bh >> 4, h = bh & 15;
  const int q0 = blockIdx.x * 128 + w * 32;
  const short* qp = qb + (size_t)bh * (N_ * D_);
  const short* kp = kb + (size_t)bh * (N_ * D_);
  const short* vp = vt + (size_t)bh * (D_ * N_);

  s16x8 qf[2][2];
  #pragma unroll
  for (int mf = 0; mf < 2; ++mf)
    #pragma unroll
    for (int kk = 0; kk < 2; ++kk)
      qf[mf][kk] = *(const s16x8*)&qp[(q0 + mf * 16 + (l & 15)) * 64 + kk * 32 + ((l >> 4) * 8)];

  f32x4 aco[2][4];
  float rm[2][4], rl[2][4];
  const f32x4 z4 = {0.f, 0.f, 0.f, 0.f};
  #pragma unroll
  for (int mf = 0; mf < 2; ++mf) {
    #pragma unroll
    for (int nd = 0; nd < 4; ++nd) aco[mf][nd] = z4;
    #pragma unroll
    for (int i = 0; i < 4; ++i) { rm[mf][i] = -1e30f; rl[mf][i] = 0.f; }
  }

  const int sr = t >> 2, sc = (t & 3) * 2;
  s16x8 rk[2], rv[2];
  #pragma unroll
  for (int p = 0; p < 2; ++p) {
    rk[p] = *(const s16x8*)&kp[sr * 64 + (sc + p) * 8];
    rv[p] = *(const s16x8*)&vp[sr * 1024 + (sc + p) * 8];
  }

  for (int kt = 0; kt < 16; ++kt) {
    if (kt) __syncthreads();
    #pragma unroll
    for (int p = 0; p < 2; ++p) {
      const int cs = ((sc + p) ^ (sr & 7)) << 3;
      *(s16x8*)&Ks[sr * 64 + cs] = rk[p];
      *(s16x8*)&Vs[sr * 64 + cs] = rv[p];
    }
    __syncthreads();
    if (kt < 15) {
      const int kv0 = (kt + 1) * 64;
      #pragma unroll
      for (int p = 0; p < 2; ++p) {
        rk[p] = *(const s16x8*)&kp[(kv0 + sr) * 64 + (sc + p) * 8];
        rv[p] = *(const s16x8*)&vp[sr * 1024 + kv0 + (sc + p) * 8];
      }
    }

    f32x4 s[2][4];
    #pragma unroll
    for (int mf = 0; mf < 2; ++mf)
      #pragma unroll
      for (int nf = 0; nf < 4; ++nf) s[mf][nf] = z4;

    #pragma unroll
    for (int kk = 0; kk < 2; ++kk) {
      const int c16 = kk * 4 + (l >> 4);
      s16x8 kf[4];
      #pragma unroll
      for (int nf = 0; nf < 4; ++nf) {
        const int r = nf * 16 + (l & 15);
        kf[nf] = *(const s16x8*)&Ks[r * 64 + ((c16 ^ (r & 7)) << 3)];
      }
      #pragma unroll
      for (int mf = 0; mf < 2; ++mf)
        #pragma unroll
        for (int nf = 0; nf < 4; ++nf)
          s[mf][nf] = __builtin_amdgcn_mfma_f32_16x16x32_bf16(qf[mf][kk], kf[nf], s[mf][nf], 0, 0, 0);
    }

    // online softmax (rows owned per quarter-wave; reduce across the 16 lanes)
    #pragma unroll
    for (int mf = 0; mf < 2; ++mf) {
      #pragma unroll
      for (int i = 0; i < 4; ++i) {
        float pm = fmaxf(fmaxf(s[mf][0][i], s[mf][1][i]), fmaxf(s[mf][2][i], s[mf][3][i]));
        pm = fmaxf(pm, __shfl_xor(pm, 1));
        pm = fmaxf(pm, __shfl_xor(pm, 2));
        pm = fmaxf(pm, __shfl_xor(pm, 4));
        pm = fmaxf(pm, __shfl_xor(pm, 8));
        const float nm = fmaxf(rm[mf][i], pm);
        const float corr = __expf(rm[mf][i] - nm);
        rm[mf][i] = nm;
        float rs = 0.f;
        #pragma unroll
        for (int nf = 0; nf < 4; ++nf) {
          const float p = __expf(s[mf][nf][i] - nm);
          s[mf][nf][i] = p;
          rs += p;
        }
        rs += __shfl_xor(rs, 1);
        rs += __shfl_xor(rs, 2);
        rs += __shfl_xor(rs, 4);
        rs += __shfl_xor(rs, 8);
        rl[mf][i] = rl[mf][i] * corr + rs;
        #pragma unroll
        for (int nd = 0; nd < 4; ++nd) aco[mf][nd][i] *= corr;
      }
    }

    // write P (C-layout) to per-wave LDS, swizzled for A-layout readback
    short* pw = &Pl[w][0];
    #pragma unroll
    for (int mf = 0; mf < 2; ++mf)
      #pragma unroll
      for (int nf = 0; nf < 4; ++nf)
        #pragma unroll
        for (int i = 0; i < 4; ++i) {
          const int row = mf * 16 + ((l >> 4) << 2) + i;
          const int col = nf * 16 + (l & 15);
          pw[row * 64 + (((col >> 3) ^ (row & 7)) << 3) + (col & 7)] = f2bf(s[mf][nf][i]);
        }

    // PV
    #pragma unroll
    for (int kk = 0; kk < 2; ++kk) {
      const int c16 = kk * 4 + (l >> 4);
      s16x8 vf[4];
      #pragma unroll
      for (int nd = 0; nd < 4; ++nd) {
        const int r = nd * 16 + (l & 15);
        vf[nd] = *(const s16x8*)&Vs[r * 64 + ((c16 ^ (r & 7)) << 3)];
      }
      #pragma unroll
      for (int mf = 0; mf < 2; ++mf) {
        const int pr = mf * 16 + (l & 15);
        const s16x8 pf = *(const s16x8*)&pw[pr * 64 + ((c16 ^ (pr & 7)) << 3)];
        #pragma unroll
        for (int nd = 0; nd < 4; ++nd)
          aco[mf][nd] = __builtin_amdgcn_mfma_f32_16x16x32_bf16(pf, vf[nd], aco[mf][nd], 0, 0, 0);
      }
    }
  }

  #pragma unroll
  for (int mf = 0; mf < 2; ++mf)
    #pragma unroll
    for (int i = 0; i < 4; ++i) {
      const float inv = 1.f / rl[mf][i];
      const int row = q0 + mf * 16 + ((l >> 4) << 2) + i;
      #pragma unroll
      for (int nd = 0; nd < 4; ++nd) {
        const int col = h * 64 + nd * 16 + (l & 15);
        ob[(size_t)(b * 1024 + row) * 1024 + col] = f2bf(aco[mf][nd][i] * inv);
      }
    }
}

// ---------------- host launcher ----------------
extern "C" void kernel_launch(void* const* d_in, const int* in_sizes, int n_in,
                              void* d_out, int out_size, void* d_ws, size_t ws_size,
                              hipStream_t stream) {
  const float* x     = (const float*)d_in[0];
  const float* c     = (const float*)d_in[1];
  const float* n1w   = (const float*)d_in[2];
  const float* n2w   = (const float*)d_in[3];
  const float* qkvw  = (const float*)d_in[4];
  const float* qkvb  = (const float*)d_in[5];
  const float* qnw   = (const float*)d_in[6];
  const float* knw   = (const float*)d_in[7];
  const float* projw = (const float*)d_in[8];
  const float* projb = (const float*)d_in[9];
  const float* w12w  = (const float*)d_in[10];
  const float* w12b  = (const float*)d_in[11];
  const float* w3w   = (const float*)d_in[12];
  const float* w3b   = (const float*)d_in[13];
  const float* adaw  = (const float*)d_in[14];
  const float* adab  = (const float*)d_in[15];
  float* outp = (float*)d_out;

  char* ws = (char*)d_ws;
  size_t off = 0;
  auto alloc = [&](size_t bytes) { void* p = ws + off; off += (bytes + 255) & ~(size_t)255; return p; };
  short* WQKV = (short*)alloc(3072ull * 1024 * 2);
  short* WPROJ = (short*)alloc(1024ull * 1024 * 2);
  short* W12B = (short*)alloc(5460ull * 1024 * 2);
  short* W3B = (short*)alloc(1024ull * 2752 * 2);
  float* ADA = (float*)alloc(4ull * 6144 * 4);
  short* H1 = (short*)alloc(4096ull * 1024 * 2);
  float* QKVF = (float*)alloc(4096ull * 3072 * 4);
  short* QBF = (short*)alloc(64ull * 1024 * 64 * 2);
  short* KBF = (short*)alloc(64ull * 1024 * 64 * 2);
  short* VTB = (short*)alloc(64ull * 64 * 1024 * 2);
  short* OBF = (short*)alloc(4096ull * 1024 * 2);
  float* X1 = (float*)alloc(4096ull * 1024 * 4);
  short* H2 = (short*)alloc(4096ull * 1024 * 2);
  short* HB = (short*)alloc(4096ull * 2752 * 2);

  cvt_bf<<<2048, 256, 0, stream>>>(qkvw, WQKV, 3072 * 1024 / 4);
  cvt_bf<<<1024, 256, 0, stream>>>(projw, WPROJ, 1024 * 1024 / 4);
  cvt_bf<<<2048, 256, 0, stream>>>(w12w, W12B, 5460 * 1024 / 4);
  cvt_w3<<<dim3(11, 1024), 256, 0, stream>>>(w3w, W3B);
  ada_gemm<<<6144, 64, 0, stream>>>(c, adaw, adab, ADA);
  rmsmod<<<4096, 256, 0, stream>>>(x, n1w, ADA, 0, 1024, H1);
  gemm_bt<0><<<dim3(24, 32), 256, 0, stream>>>(H1, WQKV, 1024, 3072, qkvb, nullptr, nullptr, QKVF);
  qk_post<<<16384, 256, 0, stream>>>(QKVF, qnw, knw, QBF, KBF);
  v_trans<<<dim3(16, 64), 256, 0, stream>>>(QKVF, VTB);
  attn<<<dim3(8, 64), 256, 0, stream>>>(QBF, KBF, VTB, OBF);
  gemm_bt<1><<<dim3(8, 32), 256, 0, stream>>>(OBF, WPROJ, 1024, 1024, projb, ADA + 2048, x, X1);
  rmsmod<<<4096, 256, 0, stream>>>(X1, n2w, ADA, 3072, 4096, H2);
  gemm_w12<<<dim3(43, 32), 256, 0, stream>>>(H2, W12B, w12b, HB);
  gemm_bt<1><<<dim3(8, 32), 256, 0, stream>>>(HB, W3B, 2752, 1024, w3b, ADA + 5120, X1, outp);
}